// Round 1
// baseline (573.302 us; speedup 1.0000x reference)
//
#include <hip/hip_runtime.h>
#include <math.h>

#define NEG_INF_F (-9000000000000000.0f)
#define SLOPE 0.01f

constexpr int B_ = 128, N_ = 10000, DIN = 64, DRAW = 64;
constexpr int CHUNK = 512;
constexpr int NCHUNK = (N_ + CHUNK - 1) / CHUNK; // 20, last chunk = 272 rows (multiple of 16)

// Pass 1: branchless streaming. e[b,n] = leakyrelu(cb + raw_x[b,n,:].a2) masked to
// NEG_INF where adj==0, stored for ALL n. Track per-chunk max only (no exp in loop).
// Layout: 16 lanes per row (16 x float4 = 256B row), 4 rows per 1KB wave load.
// 4 independent 1KB loads in flight per wave per iteration (16 rows / wave / iter).
__global__ __launch_bounds__(256) void pass1_kernel(
    const float* __restrict__ x, const float* __restrict__ raw_x,
    const float* __restrict__ a, const float* __restrict__ adj,
    const int* __restrict__ node_index, const int* __restrict__ type_index,
    float* __restrict__ e_buf, float* __restrict__ pm)
{
    const int b = blockIdx.y;
    const int cblk = blockIdx.x;
    const int tid = threadIdx.x;
    const int wave = tid >> 6;
    const int lane = tid & 63;
    const int r = lane >> 4;   // row within a 4-row load group
    const int c = lane & 15;   // 16B chunk within row
    const int t = type_index[b];

    __shared__ float s_adj[CHUNK];
    __shared__ float s_cb;
    __shared__ float s_wmax[4];

    const int n0 = cblk * CHUNK;
    const int n1 = (n0 + CHUNK < N_) ? (n0 + CHUNK) : N_;

    for (int i = tid; i < CHUNK; i += 256) {
        const int n = n0 + i;
        s_adj[i] = (n < N_) ? adj[n] : 0.f;
    }

    if (tid < 64) {
        const int ni = node_index[0];
        float v = x[((size_t)b * N_ + ni) * DIN + tid] * a[t * 128 + tid];
        for (int off = 32; off > 0; off >>= 1) v += __shfl_down(v, off);
        if (tid == 0) s_cb = v;
    }
    __syncthreads();
    const float cb = s_cb;

    // per-lane slice of a2: lane only ever touches a2[c*4 .. c*4+3]
    const float4 a2 = *(const float4*)(a + t * 128 + 64 + c * 4);

    float m = NEG_INF_F;

    const float* rxb = raw_x + (size_t)b * N_ * DRAW;
    float* eb = e_buf + (size_t)b * N_;

    // wave unit = 16 rows (4 x 1KB loads); waves stride 64 rows.
    // (n1-n0) is 512 or 272, both multiples of 16 -> units fully in-bounds.
    for (int base = n0 + wave * 16; base < n1; base += 64) {
        const float4 v0 = *(const float4*)(rxb + (size_t)(base +  0) * DRAW + lane * 4);
        const float4 v1 = *(const float4*)(rxb + (size_t)(base +  4) * DRAW + lane * 4);
        const float4 v2 = *(const float4*)(rxb + (size_t)(base +  8) * DRAW + lane * 4);
        const float4 v3 = *(const float4*)(rxb + (size_t)(base + 12) * DRAW + lane * 4);

        {
            float acc = v0.x * a2.x + v0.y * a2.y + v0.z * a2.z + v0.w * a2.w;
            acc += __shfl_xor(acc, 1); acc += __shfl_xor(acc, 2);
            acc += __shfl_xor(acc, 4); acc += __shfl_xor(acc, 8);
            float e = cb + acc;
            e = (e > 0.f) ? e : SLOPE * e;
            e = (s_adj[base - n0 + 0 + r] > 0.f) ? e : NEG_INF_F;
            m = fmaxf(m, e);
            if (c == 0) eb[base + 0 + r] = e;
        }
        {
            float acc = v1.x * a2.x + v1.y * a2.y + v1.z * a2.z + v1.w * a2.w;
            acc += __shfl_xor(acc, 1); acc += __shfl_xor(acc, 2);
            acc += __shfl_xor(acc, 4); acc += __shfl_xor(acc, 8);
            float e = cb + acc;
            e = (e > 0.f) ? e : SLOPE * e;
            e = (s_adj[base - n0 + 4 + r] > 0.f) ? e : NEG_INF_F;
            m = fmaxf(m, e);
            if (c == 0) eb[base + 4 + r] = e;
        }
        {
            float acc = v2.x * a2.x + v2.y * a2.y + v2.z * a2.z + v2.w * a2.w;
            acc += __shfl_xor(acc, 1); acc += __shfl_xor(acc, 2);
            acc += __shfl_xor(acc, 4); acc += __shfl_xor(acc, 8);
            float e = cb + acc;
            e = (e > 0.f) ? e : SLOPE * e;
            e = (s_adj[base - n0 + 8 + r] > 0.f) ? e : NEG_INF_F;
            m = fmaxf(m, e);
            if (c == 0) eb[base + 8 + r] = e;
        }
        {
            float acc = v3.x * a2.x + v3.y * a2.y + v3.z * a2.z + v3.w * a2.w;
            acc += __shfl_xor(acc, 1); acc += __shfl_xor(acc, 2);
            acc += __shfl_xor(acc, 4); acc += __shfl_xor(acc, 8);
            float e = cb + acc;
            e = (e > 0.f) ? e : SLOPE * e;
            e = (s_adj[base - n0 + 12 + r] > 0.f) ? e : NEG_INF_F;
            m = fmaxf(m, e);
            if (c == 0) eb[base + 12 + r] = e;
        }
    }

    // block max reduction (max only -- no (m,s) merge needed)
    for (int off = 32; off > 0; off >>= 1) m = fmaxf(m, __shfl_xor(m, off));
    if (lane == 0) s_wmax[wave] = m;
    __syncthreads();
    if (tid == 0) {
        pm[b * NCHUNK + cblk] =
            fmaxf(fmaxf(s_wmax[0], s_wmax[1]), fmaxf(s_wmax[2], s_wmax[3]));
    }
}

// Pass 2: per-b -- merge chunk maxes, one sweep over e_buf row computing exp(e-M)
// (kept in registers), block-reduce the sum, then write normalized output.
// Masked rows hold NEG_INF -> exp underflows to exactly 0, matching
// softmax(masked)*adj since adj is {0,1}.
__global__ __launch_bounds__(256) void pass2_kernel(
    const float* __restrict__ e_buf, const float* __restrict__ pm,
    float* __restrict__ out)
{
    const int b = blockIdx.x;
    const int tid = threadIdx.x;
    const int lane = tid & 63;
    const int wave = tid >> 6;

    __shared__ float sM, sInv;
    __shared__ float s_red[4];

    float m = NEG_INF_F;
    if (tid < NCHUNK) m = pm[b * NCHUNK + tid];
    if (tid < 64) {
        for (int off = 32; off > 0; off >>= 1) m = fmaxf(m, __shfl_down(m, off));
        if (tid == 0) sM = m;
    }
    __syncthreads();
    const float M = sM;

    const float4* e4 = (const float4*)(e_buf + (size_t)b * N_);
    float4* o4 = (float4*)(out + (size_t)b * N_);
    constexpr int NV = N_ / 4; // 2500

    float4 vals[10];
    float s = 0.f;
#pragma unroll
    for (int k = 0; k < 10; ++k) {
        const int idx = tid + k * 256;
        if (idx < NV) {
            float4 v = e4[idx];
            v.x = __expf(v.x - M);
            v.y = __expf(v.y - M);
            v.z = __expf(v.z - M);
            v.w = __expf(v.w - M);
            vals[k] = v;
            s += v.x + v.y + v.z + v.w;
        }
    }

    for (int off = 32; off > 0; off >>= 1) s += __shfl_down(s, off);
    if (lane == 0) s_red[wave] = s;
    __syncthreads();
    if (tid == 0) {
        const float tot = s_red[0] + s_red[1] + s_red[2] + s_red[3];
        sInv = 1.f / tot;
    }
    __syncthreads();
    const float inv = sInv;

#pragma unroll
    for (int k = 0; k < 10; ++k) {
        const int idx = tid + k * 256;
        if (idx < NV) {
            float4 v = vals[k];
            v.x *= inv; v.y *= inv; v.z *= inv; v.w *= inv;
            o4[idx] = v;
        }
    }
}

extern "C" void kernel_launch(void* const* d_in, const int* in_sizes, int n_in,
                              void* d_out, int out_size, void* d_ws, size_t ws_size,
                              hipStream_t stream) {
    const float* x     = (const float*)d_in[0];
    const float* raw_x = (const float*)d_in[1];
    const float* a     = (const float*)d_in[2];
    const float* adj   = (const float*)d_in[3];
    const int* node_index = (const int*)d_in[4];
    const int* type_index = (const int*)d_in[5];
    float* out = (float*)d_out;

    float* e_buf = (float*)d_ws;                       // B*N
    float* pm    = e_buf + (size_t)B_ * N_;            // B*NCHUNK (fits old B*2*10 slot)

    dim3 g1(NCHUNK, B_);
    pass1_kernel<<<g1, 256, 0, stream>>>(x, raw_x, a, adj, node_index, type_index,
                                         e_buf, pm);
    pass2_kernel<<<dim3(B_), 256, 0, stream>>>(e_buf, pm, out);
}

// Round 2
// 534.665 us; speedup vs baseline: 1.0723x; 1.0723x over previous
//
#include <hip/hip_runtime.h>
#include <math.h>

#define NEG_INF_F (-9000000000000000.0f)
#define SLOPE 0.01f

constexpr int B_ = 128, N_ = 10000, DIN = 64, DRAW = 64;
constexpr int CHUNK = 1024;
constexpr int NCHUNK = (N_ + CHUNK - 1) / CHUNK; // 10

// Pass 1: e[b,n] = leakyrelu(cb + raw_x[b,n,:].a2) for active rows; online (m,s).
// Predicated loads: exec-masked float4 loads skip HBM fetch for inactive rows
// (~50% traffic saved, adj is {0,1} uniform). 4 independent 1KB wave-loads in
// flight per iteration (16 rows/wave/iter), predicates+loads hoisted to the top.
__global__ __launch_bounds__(256) void pass1_kernel(
    const float* __restrict__ x, const float* __restrict__ raw_x,
    const float* __restrict__ a, const float* __restrict__ adj,
    const int* __restrict__ node_index, const int* __restrict__ type_index,
    float* __restrict__ e_buf, float* __restrict__ pm, float* __restrict__ ps)
{
    const int b = blockIdx.y;
    const int cblk = blockIdx.x;
    const int tid = threadIdx.x;
    const int wave = tid >> 6;
    const int lane = tid & 63;
    const int r = lane >> 4;   // row within a 4-row load group
    const int c = lane & 15;   // 16B chunk within row
    const int t = type_index[b];

    __shared__ float s_adj[CHUNK];
    __shared__ float s_cb;

    const int n0 = cblk * CHUNK;
    const int n1 = (n0 + CHUNK < N_) ? (n0 + CHUNK) : N_;

    for (int i = tid; i < CHUNK; i += 256) {
        const int n = n0 + i;
        s_adj[i] = (n < N_) ? adj[n] : 0.f;
    }

    if (tid < 64) {
        const int ni = node_index[0];
        float v = x[((size_t)b * N_ + ni) * DIN + tid] * a[t * 128 + tid];
        for (int off = 32; off > 0; off >>= 1) v += __shfl_down(v, off);
        if (tid == 0) s_cb = v;
    }
    __syncthreads();
    const float cb = s_cb;

    // per-lane slice of a2: lane only ever touches a2[c*4 .. c*4+3]
    const float4 a2 = *(const float4*)(a + t * 128 + 64 + c * 4);

    float m = NEG_INF_F, s = 0.f;

    const float* rxb = raw_x + (size_t)b * N_ * DRAW;
    float* eb = e_buf + (size_t)b * N_;

    // wave unit = 16 rows; waves stride 64 rows. (n1-n0) is 1024 or 784, both
    // multiples of 16, so every 16-row unit with base < n1 is fully in-bounds.
    for (int base = n0 + wave * 16; base < n1; base += 64) {
        const int i0 = base - n0;
        const bool act0 = s_adj[i0 +  0 + r] > 0.f;   // uniform per 16-lane group
        const bool act1 = s_adj[i0 +  4 + r] > 0.f;
        const bool act2 = s_adj[i0 +  8 + r] > 0.f;
        const bool act3 = s_adj[i0 + 12 + r] > 0.f;

        float4 v0, v1, v2, v3;
        if (act0) v0 = *(const float4*)(rxb + (size_t)(base +  0) * DRAW + lane * 4);
        if (act1) v1 = *(const float4*)(rxb + (size_t)(base +  4) * DRAW + lane * 4);
        if (act2) v2 = *(const float4*)(rxb + (size_t)(base +  8) * DRAW + lane * 4);
        if (act3) v3 = *(const float4*)(rxb + (size_t)(base + 12) * DRAW + lane * 4);

        if (act0) {
            float acc = v0.x * a2.x + v0.y * a2.y + v0.z * a2.z + v0.w * a2.w;
            acc += __shfl_xor(acc, 1); acc += __shfl_xor(acc, 2);
            acc += __shfl_xor(acc, 4); acc += __shfl_xor(acc, 8);
            float e = cb + acc;
            e = (e > 0.f) ? e : SLOPE * e;
            const float M = fmaxf(m, e);
            s = s * __expf(m - M) + __expf(e - M);
            m = M;
            if (c == 0) eb[base + 0 + r] = e;
        }
        if (act1) {
            float acc = v1.x * a2.x + v1.y * a2.y + v1.z * a2.z + v1.w * a2.w;
            acc += __shfl_xor(acc, 1); acc += __shfl_xor(acc, 2);
            acc += __shfl_xor(acc, 4); acc += __shfl_xor(acc, 8);
            float e = cb + acc;
            e = (e > 0.f) ? e : SLOPE * e;
            const float M = fmaxf(m, e);
            s = s * __expf(m - M) + __expf(e - M);
            m = M;
            if (c == 0) eb[base + 4 + r] = e;
        }
        if (act2) {
            float acc = v2.x * a2.x + v2.y * a2.y + v2.z * a2.z + v2.w * a2.w;
            acc += __shfl_xor(acc, 1); acc += __shfl_xor(acc, 2);
            acc += __shfl_xor(acc, 4); acc += __shfl_xor(acc, 8);
            float e = cb + acc;
            e = (e > 0.f) ? e : SLOPE * e;
            const float M = fmaxf(m, e);
            s = s * __expf(m - M) + __expf(e - M);
            m = M;
            if (c == 0) eb[base + 8 + r] = e;
        }
        if (act3) {
            float acc = v3.x * a2.x + v3.y * a2.y + v3.z * a2.z + v3.w * a2.w;
            acc += __shfl_xor(acc, 1); acc += __shfl_xor(acc, 2);
            acc += __shfl_xor(acc, 4); acc += __shfl_xor(acc, 8);
            float e = cb + acc;
            e = (e > 0.f) ? e : SLOPE * e;
            const float M = fmaxf(m, e);
            s = s * __expf(m - M) + __expf(e - M);
            m = M;
            if (c == 0) eb[base + 12 + r] = e;
        }
    }

    // block-level (m, s) reduction; every lane counted each of its group's rows
    // once -> 16x redundancy, divided out below.
    __shared__ float sm[256];
    __shared__ float ss[256];
    sm[tid] = m; ss[tid] = s;
    __syncthreads();
    for (int off = 128; off > 0; off >>= 1) {
        if (tid < off) {
            const float m2 = sm[tid + off], s2 = ss[tid + off];
            const float M = fmaxf(sm[tid], m2);
            ss[tid] = ss[tid] * __expf(sm[tid] - M) + s2 * __expf(m2 - M);
            sm[tid] = M;
        }
        __syncthreads();
    }
    if (tid == 0) {
        pm[b * NCHUNK + cblk] = sm[0];
        ps[b * NCHUNK + cblk] = ss[0] * (1.f / 16.f);
    }
}

// Pass 2: merge partials (16-lane parallel) + normalize + write.
__global__ __launch_bounds__(256) void pass3_kernel(
    const float* __restrict__ e_buf, const float* __restrict__ adj,
    const float* __restrict__ pm, const float* __restrict__ ps,
    float* __restrict__ out)
{
    const int b = blockIdx.y;
    const int tid = threadIdx.x;

    __shared__ float sM, sInv;
    if (tid < 16) {
        float m = NEG_INF_F, s = 0.f;
        if (tid < NCHUNK) { m = pm[b * NCHUNK + tid]; s = ps[b * NCHUNK + tid]; }
        for (int off = 8; off > 0; off >>= 1) {
            const float m2 = __shfl_xor(m, off);
            const float s2 = __shfl_xor(s, off);
            const float M = fmaxf(m, m2);
            s = s * __expf(m - M) + s2 * __expf(m2 - M);
            m = M;
        }
        if (tid == 0) { sM = m; sInv = 1.f / s; }
    }
    __syncthreads();
    const float M = sM, inv = sInv;

    const int idx4 = blockIdx.x * 256 + tid;            // float4 index
    if (idx4 >= N_ / 4) return;                          // N_=10000 -> 2500 float4s
    const float4 a4 = ((const float4*)adj)[idx4];
    const float4 e4 = ((const float4*)(e_buf + (size_t)b * N_))[idx4];
    float4 o;
    o.x = (a4.x > 0.f) ? __expf(e4.x - M) * inv : 0.f;
    o.y = (a4.y > 0.f) ? __expf(e4.y - M) * inv : 0.f;
    o.z = (a4.z > 0.f) ? __expf(e4.z - M) * inv : 0.f;
    o.w = (a4.w > 0.f) ? __expf(e4.w - M) * inv : 0.f;
    ((float4*)(out + (size_t)b * N_))[idx4] = o;
}

extern "C" void kernel_launch(void* const* d_in, const int* in_sizes, int n_in,
                              void* d_out, int out_size, void* d_ws, size_t ws_size,
                              hipStream_t stream) {
    const float* x     = (const float*)d_in[0];
    const float* raw_x = (const float*)d_in[1];
    const float* a     = (const float*)d_in[2];
    const float* adj   = (const float*)d_in[3];
    const int* node_index = (const int*)d_in[4];
    const int* type_index = (const int*)d_in[5];
    float* out = (float*)d_out;

    float* e_buf = (float*)d_ws;                       // B*N
    float* pm    = e_buf + (size_t)B_ * N_;            // B*NCHUNK
    float* ps    = pm + (size_t)B_ * NCHUNK;           // B*NCHUNK

    dim3 g1(NCHUNK, B_);
    pass1_kernel<<<g1, 256, 0, stream>>>(x, raw_x, a, adj, node_index, type_index,
                                         e_buf, pm, ps);
    dim3 g3((N_ / 4 + 255) / 256, B_);
    pass3_kernel<<<g3, 256, 0, stream>>>(e_buf, adj, pm, ps, out);
}